// Round 7
// baseline (221.481 us; speedup 1.0000x reference)
//
#include <hip/hip_runtime.h>

// NonLocalBlock B=8, L=2048, C=512, CI=256 (fp32 in/out).
// Round 7: score_softmax barrier economy. K=256 fits LDS entirely:
// stage FULL-K A,B tiles per batch (32 KB each, 64 KB total, 2 blocks/CU).
// Barriers/block: 64 -> 16 (2 per b); MFMAs per barrier-pair: 8 -> 32/wave.
// All-fp16, XOR k-chunk swizzle. proj/out/cvt unchanged from round 6.

#define NB 8
#define NL 2048
#define NC 512
#define NCI 256

using f16x8 = __attribute__((ext_vector_type(8))) _Float16;
using f32x4 = __attribute__((ext_vector_type(4))) float;
typedef unsigned short u16;

__device__ __forceinline__ u16 f16b(float x) {
    _Float16 h = (_Float16)x;
    return __builtin_bit_cast(u16, h);
}
__device__ __forceinline__ float f16tof(u16 u) {
    return (float)__builtin_bit_cast(_Float16, u);
}
__device__ __forceinline__ void gload16(const void* g, void* l) {
    __builtin_amdgcn_global_load_lds((__attribute__((address_space(1))) void*)g,
                                     (__attribute__((address_space(3))) void*)l,
                                     16, 0, 0);
}

// ---- cvt: X fp32 -> fp16 --------------------------------------------------
__global__ __launch_bounds__(256) void cvt_x_kernel(const float* __restrict__ X,
                                                    u16* __restrict__ Xf)
{
    size_t i = (size_t)blockIdx.x * 256 + threadIdx.x;   // per 8 elements
    const float4* X4 = (const float4*)X;
    float4 a = X4[2 * i], b = X4[2 * i + 1];
    u16 o[8] = {f16b(a.x), f16b(a.y), f16b(a.z), f16b(a.w),
                f16b(b.x), f16b(b.y), f16b(b.z), f16b(b.w)};
    ((uint4*)Xf)[i] = *(const uint4*)o;
}

// ---- cvt: transpose weights to [n][k] fp16 --------------------------------
__global__ __launch_bounds__(256) void cvt_w_kernel(
    const float* __restrict__ Wx, const float* __restrict__ Wy, const float* __restrict__ Wo,
    u16* __restrict__ WxT, u16* __restrict__ WyT, u16* __restrict__ WoT)
{
    const int bid = blockIdx.x, t = threadIdx.x;
#pragma unroll
    for (int kk = 0; kk < 2; ++kk) {
        const int k = t + kk * 256;
        if (bid < 256)      WxT[(size_t)bid * NC + k] = f16b(Wx[(size_t)k * NCI + bid]);
        else if (bid < 512) WyT[(size_t)(bid - 256) * NC + k] = f16b(Wy[(size_t)k * NCI + (bid - 256)]);
        else                WoT[(size_t)(bid - 512) * NC + k] = f16b(Wo[(size_t)k * NC + (bid - 512)]);
    }
}

// ---- projections: grid (128, 8); cb 0-1 xp, 2-3 yp, 4-7 op (transposed) ----
__global__ __launch_bounds__(256) void proj_kernel(
    const u16* __restrict__ Xf,
    const u16* __restrict__ WxT, const u16* __restrict__ WyT, const u16* __restrict__ WoT,
    const float* __restrict__ bx, const float* __restrict__ by, const float* __restrict__ bo,
    u16* __restrict__ xp, u16* __restrict__ yp, u16* __restrict__ opT)
{
    __shared__ __align__(16) u16 SM[17408];   // As 8192 + Bs 8192; Ts reuse 128x136
    u16* As = SM;
    u16* Bs = SM + 8192;

    const int tid = threadIdx.x;
    const int w = tid >> 6, lane = tid & 63;
    const int row0 = blockIdx.x * 128;
    const int cb = blockIdx.y;

    const u16* W; const float* bias; int n0, path;
    if (cb < 2)      { path = 0; n0 = cb * 128;       W = WxT; bias = bx; }
    else if (cb < 4) { path = 1; n0 = (cb - 2) * 128; W = WyT; bias = by; }
    else             { path = 2; n0 = (cb - 4) * 128; W = WoT; bias = bo; }

    f32x4 acc[4][4] = {};
    const int wm = (w & 1) * 64, wn = (w >> 1) * 64;
    const int fr = lane & 15, fq = lane >> 4;

    for (int k0 = 0; k0 < NC; k0 += 64) {
#pragma unroll
        for (int pass = 0; pass < 4; ++pass) {
            const int cbase = pass * 256 + w * 64;   // wave-uniform
            const int chunk = cbase + lane;
            const int r = chunk >> 3;
            const int kc = (chunk & 7) ^ (r & 7);    // XOR-swizzled k-chunk
            gload16(Xf + (size_t)(row0 + r) * NC + k0 + kc * 8, (char*)As + cbase * 16);
            gload16(W  + (size_t)(n0  + r) * NC + k0 + kc * 8, (char*)Bs + cbase * 16);
        }
        __syncthreads();
        f16x8 a[4][2], b[4][2];
#pragma unroll
        for (int mi = 0; mi < 4; ++mi)
#pragma unroll
            for (int kt = 0; kt < 2; ++kt)
                a[mi][kt] = *(const f16x8*)&As[(wm + mi * 16 + fr) * 64 + ((kt * 4 + fq) ^ (fr & 7)) * 8];
#pragma unroll
        for (int ni = 0; ni < 4; ++ni)
#pragma unroll
            for (int kt = 0; kt < 2; ++kt)
                b[ni][kt] = *(const f16x8*)&Bs[(wn + ni * 16 + fr) * 64 + ((kt * 4 + fq) ^ (fr & 7)) * 8];
#pragma unroll
        for (int kt = 0; kt < 2; ++kt)
#pragma unroll
            for (int mi = 0; mi < 4; ++mi)
#pragma unroll
                for (int ni = 0; ni < 4; ++ni)
                    acc[mi][ni] = __builtin_amdgcn_mfma_f32_16x16x32_f16(a[mi][kt], b[ni][kt], acc[mi][ni], 0, 0, 0);
        __syncthreads();
    }

    if (path != 2) {
        u16* O = (path == 0) ? xp : yp;
#pragma unroll
        for (int mi = 0; mi < 4; ++mi) {
            const int grow = row0 + wm + mi * 16 + fq * 4;
#pragma unroll
            for (int ni = 0; ni < 4; ++ni) {
                const int gcol = n0 + wn + ni * 16 + fr;
                const float bv = bias[gcol];
#pragma unroll
                for (int r = 0; r < 4; ++r)
                    O[(size_t)(grow + r) * NCI + gcol] = f16b(acc[mi][ni][r] + bv);
            }
        }
    } else {
        u16* Ts = SM;   // 128 x 136 fp16 transpose staging
#pragma unroll
        for (int mi = 0; mi < 4; ++mi) {
            const int mb = wm + mi * 16 + fq * 4;
#pragma unroll
            for (int ni = 0; ni < 4; ++ni) {
                const int nl_ = wn + ni * 16 + fr;
                const float bv = bias[n0 + nl_];
#pragma unroll
                for (int r = 0; r < 4; ++r)
                    Ts[nl_ * 136 + mb + r] = f16b(acc[mi][ni][r] + bv);
            }
        }
        __syncthreads();
        const int b = row0 >> 11, m0 = row0 & 2047;
        u16* dst = opT + (size_t)b * NC * NL + (size_t)n0 * NL + m0;
        for (int i = tid; i < 128 * 16; i += 256) {
            const int c = i >> 4, ch = i & 15;
            uint4 v = *(const uint4*)&Ts[c * 136 + ch * 8];
            *(uint4*)&dst[(size_t)c * NL + ch * 8] = v;
        }
    }
}

// ---- FUSED score+softmax, FULL-K staging ----------------------------------
// Grid (32,32), 256 thr / 4 waves. Block = one 64x64 (l,m) tile, ALL 8 b.
// Per b: stage A(64x256) + B(64x256) fp16 (64 KB LDS), ONE barrier pair,
// 32 MFMAs/wave. Wave tile 64(m) x 16(n); per thread 16 C/D x 8 b packed.
__global__ __launch_bounds__(256) void score_softmax_kernel(
    const u16* __restrict__ xp, const u16* __restrict__ yp, u16* __restrict__ ATT)
{
    __shared__ __align__(16) u16 As[64 * 256], Bs[64 * 256];   // 32 KB each
    const int tid = threadIdx.x;
    const int w = tid >> 6, lane = tid & 63;
    const int row0 = blockIdx.x * 64, col0 = blockIdx.y * 64;
    const int wn = w * 16;
    const int fr = lane & 15, fq = lane >> 4;

    unsigned sv[NB][8];   // [b][mi*2+rp]: lo half r=rp*2, hi half r=rp*2+1

#pragma unroll 1
    for (int b = 0; b < NB; ++b) {
        const u16* A = xp + (size_t)b * NL * NCI;
        const u16* B = yp + (size_t)b * NL * NCI;
        // stage full K: 64 rows x 32 k-chunks(16B) = 2048 chunks per tile;
        // 256 lanes -> 8 passes. LDS[r][j] = global[r][j ^ (r&31)].
#pragma unroll
        for (int pass = 0; pass < 8; ++pass) {
            const int cbase = pass * 256 + w * 64;   // wave-uniform
            const int chunk = cbase + lane;
            const int r = chunk >> 5;
            const int kc = (chunk & 31) ^ (r & 31);
            gload16(A + (size_t)(row0 + r) * NCI + kc * 8, (char*)As + cbase * 16);
            gload16(B + (size_t)(col0 + r) * NCI + kc * 8, (char*)Bs + cbase * 16);
        }
        __syncthreads();
        f32x4 acc[4] = {};
#pragma unroll
        for (int kt = 0; kt < 8; ++kt) {
            f16x8 af[4], bf;
#pragma unroll
            for (int mi = 0; mi < 4; ++mi) {
                const int row = mi * 16 + fr;
                af[mi] = *(const f16x8*)&As[row * 256 + ((kt * 4 + fq) ^ (row & 31)) * 8];
            }
            {
                const int row = wn + fr;
                bf = *(const f16x8*)&Bs[row * 256 + ((kt * 4 + fq) ^ (row & 31)) * 8];
            }
#pragma unroll
            for (int mi = 0; mi < 4; ++mi)
                acc[mi] = __builtin_amdgcn_mfma_f32_16x16x32_f16(af[mi], bf, acc[mi], 0, 0, 0);
        }
        __syncthreads();
#pragma unroll
        for (int mi = 0; mi < 4; ++mi) {
            sv[b][mi * 2 + 0] = (unsigned)f16b(acc[mi][0]) | ((unsigned)f16b(acc[mi][1]) << 16);
            sv[b][mi * 2 + 1] = (unsigned)f16b(acc[mi][2]) | ((unsigned)f16b(acc[mi][3]) << 16);
        }
    }

    // register-only softmax over b, then write attn fp16
    const int gc = col0 + wn + fr;
#pragma unroll
    for (int mi = 0; mi < 4; ++mi) {
#pragma unroll
        for (int rp = 0; rp < 2; ++rp) {
            float v0[NB], v1[NB];
#pragma unroll
            for (int b = 0; b < NB; ++b) {
                unsigned u = sv[b][mi * 2 + rp];
                v0[b] = f16tof((u16)(u & 0xFFFF));
                v1[b] = f16tof((u16)(u >> 16));
            }
            float m0 = v0[0], m1 = v1[0];
#pragma unroll
            for (int b = 1; b < NB; ++b) { m0 = fmaxf(m0, v0[b]); m1 = fmaxf(m1, v1[b]); }
            float s0 = 0.f, s1 = 0.f;
#pragma unroll
            for (int b = 0; b < NB; ++b) {
                v0[b] = __expf(v0[b] - m0); s0 += v0[b];
                v1[b] = __expf(v1[b] - m1); s1 += v1[b];
            }
            const float i0 = 1.f / s0, i1 = 1.f / s1;
            const int gr0 = row0 + mi * 16 + fq * 4 + rp * 2;
#pragma unroll
            for (int b = 0; b < NB; ++b) {
                u16* dst = ATT + (size_t)b * NL * NL;
                dst[(size_t)gr0 * NL + gc]       = f16b(v0[b] * i0);
                dst[(size_t)(gr0 + 1) * NL + gc] = f16b(v1[b] * i1);
            }
        }
    }
}

// ---- out: out[b] = X[b] + attn[b] @ op[b], 512 thr, issue-early dbuf -------
__global__ __launch_bounds__(512) void out_kernel(
    const u16* __restrict__ ATT, const u16* __restrict__ opT,
    const float* __restrict__ X, float* __restrict__ Out)
{
    __shared__ __align__(16) u16 As[2][8192], Bs[2][8192];   // 128 x 64 each, x2
    const int tid = threadIdx.x;
    const int w = tid >> 6, lane = tid & 63;
    const int b = blockIdx.z;
    const int row0 = blockIdx.x * 128, col0 = blockIdx.y * 128;
    const u16* Aatt = ATT + (size_t)b * NL * NL;
    const u16* Bsrc = opT + (size_t)b * NC * NL;

    f32x4 acc[4][2] = {};
    const int wm = (w & 1) * 64, wn = (w >> 1) * 32;
    const int fr = lane & 15, fq = lane >> 4;

    auto stage = [&](int k0, int bu) {
#pragma unroll
        for (int pass = 0; pass < 2; ++pass) {
            const int cbase = pass * 512 + w * 64;   // wave-uniform
            const int chunk = cbase + lane;
            const int r = chunk >> 3;
            const int kc = (chunk & 7) ^ (r & 7);
            gload16(Aatt + (size_t)(row0 + r) * NL + k0 + kc * 8, (char*)&As[bu][0] + cbase * 16);
            gload16(Bsrc + (size_t)(col0 + r) * NL + k0 + kc * 8, (char*)&Bs[bu][0] + cbase * 16);
        }
    };

    stage(0, 0);
    int bu = 0;
    for (int it = 0; it < NL / 64; ++it) {
        __syncthreads();                         // buf[bu] ready
        if (it + 1 < NL / 64) stage((it + 1) * 64, bu ^ 1);   // fly during compute
        f16x8 af[4][2], bf[2][2];
#pragma unroll
        for (int mi = 0; mi < 4; ++mi)
#pragma unroll
            for (int kt = 0; kt < 2; ++kt)
                af[mi][kt] = *(const f16x8*)&As[bu][(wm + mi * 16 + fr) * 64 + ((kt * 4 + fq) ^ (fr & 7)) * 8];
#pragma unroll
        for (int ni = 0; ni < 2; ++ni)
#pragma unroll
            for (int kt = 0; kt < 2; ++kt)
                bf[ni][kt] = *(const f16x8*)&Bs[bu][(wn + ni * 16 + fr) * 64 + ((kt * 4 + fq) ^ (fr & 7)) * 8];
#pragma unroll
        for (int kt = 0; kt < 2; ++kt)
#pragma unroll
            for (int mi = 0; mi < 4; ++mi)
#pragma unroll
                for (int ni = 0; ni < 2; ++ni)
                    acc[mi][ni] = __builtin_amdgcn_mfma_f32_16x16x32_f16(af[mi][kt], bf[ni][kt], acc[mi][ni], 0, 0, 0);
        bu ^= 1;
    }
    const size_t ob = (size_t)b * NL * NC;
#pragma unroll
    for (int mi = 0; mi < 4; ++mi) {
        const int gr = row0 + wm + mi * 16 + fq * 4;
#pragma unroll
        for (int ni = 0; ni < 2; ++ni) {
            const int gc = col0 + wn + ni * 16 + fr;
#pragma unroll
            for (int r = 0; r < 4; ++r) {
                const size_t o = ob + (size_t)(gr + r) * NC + gc;
                Out[o] = X[o] + acc[mi][ni][r];
            }
        }
    }
}

extern "C" void kernel_launch(void* const* d_in, const int* in_sizes, int n_in,
                              void* d_out, int out_size, void* d_ws, size_t ws_size,
                              hipStream_t stream)
{
    const float* X  = (const float*)d_in[0];
    const float* Wx = (const float*)d_in[1];
    const float* bx = (const float*)d_in[2];
    const float* Wy = (const float*)d_in[3];
    const float* by = (const float*)d_in[4];
    const float* Wo = (const float*)d_in[5];
    const float* bo = (const float*)d_in[6];
    float* out = (float*)d_out;

    // Workspace (~97 MB): ATT fp16 [0,64MB); Xf16 (16MB) overlaps ATT[0:16MB) —
    // dead (proj done) before score_softmax writes ATT (stream-ordered).
    char* ws = (char*)d_ws;
    u16* ATT = (u16*)ws;
    u16* Xf  = (u16*)ws;
    char* p = ws + 67108864;
    u16* xp  = (u16*)p; p += 8388608;
    u16* yp  = (u16*)p; p += 8388608;
    u16* opT = (u16*)p; p += 16777216;
    u16* WxT = (u16*)p; p += 262144;
    u16* WyT = (u16*)p; p += 262144;
    u16* WoT = (u16*)p; p += 524288;

    cvt_x_kernel<<<4096, 256, 0, stream>>>(X, Xf);
    cvt_w_kernel<<<1024, 256, 0, stream>>>(Wx, Wy, Wo, WxT, WyT, WoT);
    proj_kernel<<<dim3(128, 8), 256, 0, stream>>>(Xf, WxT, WyT, WoT, bx, by, bo, xp, yp, opT);
    score_softmax_kernel<<<dim3(32, 32), 256, 0, stream>>>(xp, yp, ATT);
    out_kernel<<<dim3(16, 4, NB), 512, 0, stream>>>(ATT, opT, X, out);
}

// Round 9
// 219.090 us; speedup vs baseline: 1.0109x; 1.0109x over previous
//
#include <hip/hip_runtime.h>

// NonLocalBlock B=8, L=2048, C=512, CI=256 (fp32 in/out).
// Round 9 (= round 8 fixed): no LDS-pointer arrays (gfx950 addrspacecast
// static-init error) — double-buffer base computed as SM + bu*4096.
// Un-fused score/softmax; unified GEMM structure: BK=32 issue-early LDS
// double-buffer (32 KB -> 4 blocks/CU on 512-thr kernels), XOR swizzle
// (chunk&3)^((r>>1)&3) => <=2-way LDS (free). Score epilogue assembles the
// fp16 tile in LDS then writes full 256B rows (no write amplification).

#define NB 8
#define NL 2048
#define NC 512
#define NCI 256

using f16x8 = __attribute__((ext_vector_type(8))) _Float16;
using f32x4 = __attribute__((ext_vector_type(4))) float;
typedef unsigned short u16;

__device__ __forceinline__ u16 f16b(float x) {
    _Float16 h = (_Float16)x;
    return __builtin_bit_cast(u16, h);
}
__device__ __forceinline__ void gload16(const void* g, void* l) {
    __builtin_amdgcn_global_load_lds((__attribute__((address_space(1))) void*)g,
                                     (__attribute__((address_space(3))) void*)l,
                                     16, 0, 0);
}

// ---- cvt: X fp32->fp16 (bid<4096) and W transpose+cvt (bid>=4096) ----------
__global__ __launch_bounds__(256) void cvt_kernel(
    const float* __restrict__ X, u16* __restrict__ Xf,
    const float* __restrict__ Wx, const float* __restrict__ Wy, const float* __restrict__ Wo,
    u16* __restrict__ WxT, u16* __restrict__ WyT, u16* __restrict__ WoT)
{
    const int bid = blockIdx.x;
    if (bid < 4096) {
        size_t i = (size_t)bid * 256 + threadIdx.x;   // per 8 elements
        const float4* X4 = (const float4*)X;
        float4 a = X4[2 * i], b = X4[2 * i + 1];
        u16 o[8] = {f16b(a.x), f16b(a.y), f16b(a.z), f16b(a.w),
                    f16b(b.x), f16b(b.y), f16b(b.z), f16b(b.w)};
        ((uint4*)Xf)[i] = *(const uint4*)o;
    } else {
        const int wb = bid - 4096, t = threadIdx.x;
#pragma unroll
        for (int kk = 0; kk < 2; ++kk) {
            const int k = t + kk * 256;
            if (wb < 256)      WxT[(size_t)wb * NC + k] = f16b(Wx[(size_t)k * NCI + wb]);
            else if (wb < 512) WyT[(size_t)(wb - 256) * NC + k] = f16b(Wy[(size_t)k * NCI + (wb - 256)]);
            else               WoT[(size_t)(wb - 512) * NC + k] = f16b(Wo[(size_t)k * NC + (wb - 512)]);
        }
    }
}

// ---- projections: grid (128, 8); 256 thr / 4 waves; BK=32 dbuf -------------
__global__ __launch_bounds__(256) void proj_kernel(
    const u16* __restrict__ Xf,
    const u16* __restrict__ WxT, const u16* __restrict__ WyT, const u16* __restrict__ WoT,
    const float* __restrict__ bx, const float* __restrict__ by, const float* __restrict__ bo,
    u16* __restrict__ xp, u16* __restrict__ yp, u16* __restrict__ opT)
{
    __shared__ __align__(16) u16 SM[17408];   // [0,8192) A dbuf, [8192,16384) B dbuf; Ts reuse
    const int tid = threadIdx.x;
    const int w = tid >> 6, lane = tid & 63;
    const int row0 = blockIdx.x * 128;
    const int cb = blockIdx.y;

    const u16* W; const float* bias; int n0, path;
    if (cb < 2)      { path = 0; n0 = cb * 128;       W = WxT; bias = bx; }
    else if (cb < 4) { path = 1; n0 = (cb - 2) * 128; W = WyT; bias = by; }
    else             { path = 2; n0 = (cb - 4) * 128; W = WoT; bias = bo; }

    f32x4 acc[4][4] = {};
    const int wm = (w & 1) * 64, wn = (w >> 1) * 64;
    const int fr = lane & 15, fq = lane >> 4;

    auto stage = [&](int k0, int bu) {
#pragma unroll
        for (int pass = 0; pass < 2; ++pass) {
            const int cbase = pass * 256 + w * 64;   // wave-uniform
            const int chunk = cbase + lane;
            const int r = chunk >> 2;
            const int kc = (chunk & 3) ^ ((r >> 1) & 3);
            gload16(Xf + (size_t)(row0 + r) * NC + k0 + kc * 8,
                    (char*)(SM + bu * 4096) + cbase * 16);
            gload16(W  + (size_t)(n0  + r) * NC + k0 + kc * 8,
                    (char*)(SM + 8192 + bu * 4096) + cbase * 16);
        }
    };

    stage(0, 0);
    int bu = 0;
    for (int it = 0; it < NC / 32; ++it) {
        __syncthreads();
        if (it + 1 < NC / 32) stage((it + 1) * 32, bu ^ 1);
        const u16* As = SM + bu * 4096;
        const u16* Bs = SM + 8192 + bu * 4096;
        f16x8 a[4], b[4];
#pragma unroll
        for (int mi = 0; mi < 4; ++mi) {
            const int row = wm + mi * 16 + fr;
            a[mi] = *(const f16x8*)&As[row * 32 + (fq ^ ((row >> 1) & 3)) * 8];
        }
#pragma unroll
        for (int ni = 0; ni < 4; ++ni) {
            const int row = wn + ni * 16 + fr;
            b[ni] = *(const f16x8*)&Bs[row * 32 + (fq ^ ((row >> 1) & 3)) * 8];
        }
#pragma unroll
        for (int mi = 0; mi < 4; ++mi)
#pragma unroll
            for (int ni = 0; ni < 4; ++ni)
                acc[mi][ni] = __builtin_amdgcn_mfma_f32_16x16x32_f16(a[mi], b[ni], acc[mi][ni], 0, 0, 0);
        bu ^= 1;
    }

    if (path != 2) {
        u16* O = (path == 0) ? xp : yp;
#pragma unroll
        for (int mi = 0; mi < 4; ++mi) {
            const int grow = row0 + wm + mi * 16 + fq * 4;
#pragma unroll
            for (int ni = 0; ni < 4; ++ni) {
                const int gcol = n0 + wn + ni * 16 + fr;
                const float bv = bias[gcol];
#pragma unroll
                for (int r = 0; r < 4; ++r)
                    O[(size_t)(grow + r) * NCI + gcol] = f16b(acc[mi][ni][r] + bv);
            }
        }
    } else {
        __syncthreads();                         // done reading dbuf tiles
        u16* Ts = SM;                            // 128 x 136 fp16 transpose staging
#pragma unroll
        for (int mi = 0; mi < 4; ++mi) {
            const int mb = wm + mi * 16 + fq * 4;
#pragma unroll
            for (int ni = 0; ni < 4; ++ni) {
                const int nl_ = wn + ni * 16 + fr;
                const float bv = bias[n0 + nl_];
#pragma unroll
                for (int r = 0; r < 4; ++r)
                    Ts[nl_ * 136 + mb + r] = f16b(acc[mi][ni][r] + bv);
            }
        }
        __syncthreads();
        const int b = row0 >> 11, m0 = row0 & 2047;
        u16* dst = opT + (size_t)b * NC * NL + (size_t)n0 * NL + m0;
        for (int i = tid; i < 128 * 16; i += 256) {
            const int c = i >> 4, ch = i & 15;
            uint4 v = *(const uint4*)&Ts[c * 136 + ch * 8];
            *(uint4*)&dst[(size_t)c * NL + ch * 8] = v;
        }
    }
}

// ---- scores: S16[b] = fp16( xp[b] @ yp[b]^T ), 512 thr, BK=32 dbuf ---------
// Wave grid 2(m) x 4(n), wave tile 64x32. Epilogue via LDS -> full-row writes.
__global__ __launch_bounds__(512) void score_kernel(
    const u16* __restrict__ xp, const u16* __restrict__ yp, u16* __restrict__ S16)
{
    __shared__ __align__(16) u16 SM[17408];
    const int tid = threadIdx.x;
    const int w = tid >> 6, lane = tid & 63;
    const int b = blockIdx.z;
    const int row0 = blockIdx.x * 128, col0 = blockIdx.y * 128;
    const size_t ab = (size_t)b * NL * NCI;
    const u16* A = xp + ab;
    const u16* B = yp + ab;

    f32x4 acc[4][2] = {};
    const int wm = (w & 1) * 64, wn = (w >> 1) * 32;
    const int fr = lane & 15, fq = lane >> 4;

    auto stage = [&](int k0, int bu) {
        const int chunk = w * 64 + lane;         // 512 chunks, one pass
        const int r = chunk >> 2;
        const int kc = (chunk & 3) ^ ((r >> 1) & 3);
        gload16(A + (size_t)(row0 + r) * NCI + k0 + kc * 8,
                (char*)(SM + bu * 4096) + chunk * 16);
        gload16(B + (size_t)(col0 + r) * NCI + k0 + kc * 8,
                (char*)(SM + 8192 + bu * 4096) + chunk * 16);
    };

    stage(0, 0);
    int bu = 0;
    for (int it = 0; it < NCI / 32; ++it) {
        __syncthreads();
        if (it + 1 < NCI / 32) stage((it + 1) * 32, bu ^ 1);
        const u16* As = SM + bu * 4096;
        const u16* Bs = SM + 8192 + bu * 4096;
        f16x8 af[4], bf[2];
#pragma unroll
        for (int mi = 0; mi < 4; ++mi) {
            const int row = wm + mi * 16 + fr;
            af[mi] = *(const f16x8*)&As[row * 32 + (fq ^ ((row >> 1) & 3)) * 8];
        }
#pragma unroll
        for (int ni = 0; ni < 2; ++ni) {
            const int row = wn + ni * 16 + fr;
            bf[ni] = *(const f16x8*)&Bs[row * 32 + (fq ^ ((row >> 1) & 3)) * 8];
        }
#pragma unroll
        for (int mi = 0; mi < 4; ++mi)
#pragma unroll
            for (int ni = 0; ni < 2; ++ni)
                acc[mi][ni] = __builtin_amdgcn_mfma_f32_16x16x32_f16(af[mi], bf[ni], acc[mi][ni], 0, 0, 0);
        bu ^= 1;
    }

    // Epilogue: assemble fp16 tile in LDS (stride 136), then coalesced writes.
    __syncthreads();
    u16* Ts = SM;
#pragma unroll
    for (int mi = 0; mi < 4; ++mi) {
        const int lr = wm + mi * 16 + fq * 4;
#pragma unroll
        for (int ni = 0; ni < 2; ++ni) {
            const int lc = wn + ni * 16 + fr;
#pragma unroll
            for (int r = 0; r < 4; ++r)
                Ts[(lr + r) * 136 + lc] = f16b(acc[mi][ni][r]);
        }
    }
    __syncthreads();
    u16* Sb = S16 + (size_t)b * NL * NL;
    for (int i = tid; i < 128 * 16; i += 512) {
        const int row = i >> 4, ch = i & 15;
        uint4 v = *(const uint4*)&Ts[row * 136 + ch * 8];
        *(uint4*)&Sb[(size_t)(row0 + row) * NL + col0 + ch * 8] = v;
    }
}

// ---- softmax over batch axis, fp16 in -> fp16 attn, IN PLACE ---------------
__global__ __launch_bounds__(256) void softmax_kernel(u16* __restrict__ S16)
{
    const size_t g = (size_t)blockIdx.x * 256 + threadIdx.x;   // uint4 group (8 u16)
    const size_t st = (size_t)NL * NL / 8;
    uint4* P = (uint4*)S16;
    uint4 raw[NB];
#pragma unroll
    for (int b = 0; b < NB; ++b) raw[b] = P[b * st + g];
    float f[NB][8];
#pragma unroll
    for (int b = 0; b < NB; ++b) {
        f16x8 h = __builtin_bit_cast(f16x8, raw[b]);
#pragma unroll
        for (int j = 0; j < 8; ++j) f[b][j] = (float)h[j];
    }
#pragma unroll
    for (int j = 0; j < 8; ++j) {
        float mx = f[0][j];
#pragma unroll
        for (int b = 1; b < NB; ++b) mx = fmaxf(mx, f[b][j]);
        float s = 0.f;
#pragma unroll
        for (int b = 0; b < NB; ++b) { f[b][j] = __expf(f[b][j] - mx); s += f[b][j]; }
        const float inv = 1.f / s;
#pragma unroll
        for (int b = 0; b < NB; ++b) f[b][j] *= inv;
    }
#pragma unroll
    for (int b = 0; b < NB; ++b) {
        u16 o[8];
#pragma unroll
        for (int j = 0; j < 8; ++j) o[j] = f16b(f[b][j]);
        P[b * st + g] = *(const uint4*)o;
    }
}

// ---- out: out[b] = X[b] + attn[b] @ op[b], 512 thr, BK=32 dbuf -------------
__global__ __launch_bounds__(512) void out_kernel(
    const u16* __restrict__ ATT, const u16* __restrict__ opT,
    const float* __restrict__ X, float* __restrict__ Out)
{
    __shared__ __align__(16) u16 SM[16384];   // [0,8192) A dbuf, [8192,16384) B dbuf
    const int tid = threadIdx.x;
    const int w = tid >> 6, lane = tid & 63;
    const int b = blockIdx.z;
    const int row0 = blockIdx.x * 128, col0 = blockIdx.y * 128;
    const u16* Aatt = ATT + (size_t)b * NL * NL;
    const u16* Bsrc = opT + (size_t)b * NC * NL;

    f32x4 acc[4][2] = {};
    const int wm = (w & 1) * 64, wn = (w >> 1) * 32;
    const int fr = lane & 15, fq = lane >> 4;

    auto stage = [&](int k0, int bu) {
        const int chunk = w * 64 + lane;         // 512 chunks, one pass
        const int r = chunk >> 2;
        const int kc = (chunk & 3) ^ ((r >> 1) & 3);
        gload16(Aatt + (size_t)(row0 + r) * NL + k0 + kc * 8,
                (char*)(SM + bu * 4096) + chunk * 16);
        gload16(Bsrc + (size_t)(col0 + r) * NL + k0 + kc * 8,
                (char*)(SM + 8192 + bu * 4096) + chunk * 16);
    };

    stage(0, 0);
    int bu = 0;
    for (int it = 0; it < NL / 32; ++it) {
        __syncthreads();
        if (it + 1 < NL / 32) stage((it + 1) * 32, bu ^ 1);
        const u16* As = SM + bu * 4096;
        const u16* Bs = SM + 8192 + bu * 4096;
        f16x8 af[4], bf[2];
#pragma unroll
        for (int mi = 0; mi < 4; ++mi) {
            const int row = wm + mi * 16 + fr;
            af[mi] = *(const f16x8*)&As[row * 32 + (fq ^ ((row >> 1) & 3)) * 8];
        }
#pragma unroll
        for (int ni = 0; ni < 2; ++ni) {
            const int row = wn + ni * 16 + fr;
            bf[ni] = *(const f16x8*)&Bs[row * 32 + (fq ^ ((row >> 1) & 3)) * 8];
        }
#pragma unroll
        for (int mi = 0; mi < 4; ++mi)
#pragma unroll
            for (int ni = 0; ni < 2; ++ni)
                acc[mi][ni] = __builtin_amdgcn_mfma_f32_16x16x32_f16(af[mi], bf[ni], acc[mi][ni], 0, 0, 0);
        bu ^= 1;
    }
    const size_t ob = (size_t)b * NL * NC;
#pragma unroll
    for (int mi = 0; mi < 4; ++mi) {
        const int gr = row0 + wm + mi * 16 + fq * 4;
#pragma unroll
        for (int ni = 0; ni < 2; ++ni) {
            const int gc = col0 + wn + ni * 16 + fr;
#pragma unroll
            for (int r = 0; r < 4; ++r) {
                const size_t o = ob + (size_t)(gr + r) * NC + gc;
                Out[o] = X[o] + acc[mi][ni][r];
            }
        }
    }
}

extern "C" void kernel_launch(void* const* d_in, const int* in_sizes, int n_in,
                              void* d_out, int out_size, void* d_ws, size_t ws_size,
                              hipStream_t stream)
{
    const float* X  = (const float*)d_in[0];
    const float* Wx = (const float*)d_in[1];
    const float* bx = (const float*)d_in[2];
    const float* Wy = (const float*)d_in[3];
    const float* by = (const float*)d_in[4];
    const float* Wo = (const float*)d_in[5];
    const float* bo = (const float*)d_in[6];
    float* out = (float*)d_out;

    // Workspace (~97 MB): S16 fp16 [0,64MB); Xf16 (32MB) overlaps — dead
    // (proj done) before score_kernel writes S16 (stream-ordered).
    char* ws = (char*)d_ws;
    u16* S16 = (u16*)ws;
    u16* Xf  = (u16*)ws;
    char* p = ws + 67108864;
    u16* xp  = (u16*)p; p += 8388608;
    u16* yp  = (u16*)p; p += 8388608;
    u16* opT = (u16*)p; p += 16777216;
    u16* WxT = (u16*)p; p += 262144;
    u16* WyT = (u16*)p; p += 262144;
    u16* WoT = (u16*)p; p += 524288;

    cvt_kernel<<<5120, 256, 0, stream>>>(X, Xf, Wx, Wy, Wo, WxT, WyT, WoT);
    proj_kernel<<<dim3(128, 8), 256, 0, stream>>>(Xf, WxT, WyT, WoT, bx, by, bo, xp, yp, opT);
    score_kernel<<<dim3(16, 16, NB), 512, 0, stream>>>(xp, yp, S16);
    softmax_kernel<<<2048, 256, 0, stream>>>(S16);
    out_kernel<<<dim3(16, 4, NB), 512, 0, stream>>>(S16, opT, X, out);
}